// Round 6
// baseline (604.952 us; speedup 1.0000x reference)
//
#include <hip/hip_runtime.h>
#include <hip/hip_bf16.h>
#include <hip/hip_fp16.h>

// GCN: 4 layers. N=100000, E=1600000, F=H=128, C=40. fp32 in/out.
// R11 changes vs R10:
//  - agg128 -> agg128_sliced: 4 feature-slices of 32 (64B/row = one fetch
//    sector), slice = blockIdx.x & 3. With round-robin block->XCD dispatch
//    (xcd = blockIdx.x % 8), slice s runs only on XCDs {s, s+4}, so each
//    XCD's L2 pulls a 6.4MB slice column instead of the whole 25.6MB table.
//    Predicted FETCH 192 -> ~80MB. Wave = 4 sub-nodes x 16 lanes
//    (agg40_tri's proven predication pattern; R8-like occupancy).
//  - R9 lesson kept: no persistent low-occupancy grids for agg128.

#define N_NODES 100000
#define N_EDGES 1600000

#define BSHIFT 7          // bucket = dst >> 7  (128 nodes / bucket)
#define BWIDTH 128
#define CELL_CAP 512      // per-(bucket,xcd-shard) capacity; mean fill ~256
#define P1_EPT 16
#define P1_CHUNK 4096     // 256 threads * 16 edges

typedef short s16x8 __attribute__((ext_vector_type(8)));
typedef _Float16 f16x8 __attribute__((ext_vector_type(8)));
typedef float f32x4 __attribute__((ext_vector_type(4)));
typedef float f32x2 __attribute__((ext_vector_type(2)));

// ---------------- CSR build (bucketed) ----------------

// Pass 1: partition edges into (bucket, blockIdx&7) cells.
__global__ __launch_bounds__(256) void pass1_bucket(const int* __restrict__ src,
                                                    const int* __restrict__ dst,
                                                    int* __restrict__ bcur2,      // [nb*8]
                                                    int2* __restrict__ cells,     // [nb*8*CELL_CAP]
                                                    int2* __restrict__ spill,
                                                    int* __restrict__ spillCnt,
                                                    int nb, int e) {
    __shared__ int hist[1024];   // nb <= 1024 (782 here)
    __shared__ int base[1024];
    int t = threadIdx.x;
    int x = blockIdx.x & 7;
    int e0 = blockIdx.x * P1_CHUNK;

    for (int i = t; i < nb; i += 256) hist[i] = 0;
    __syncthreads();

    int ds[P1_EPT], ss[P1_EPT];
#pragma unroll
    for (int j = 0; j < P1_EPT; j++) {
        int i = e0 + j * 256 + t;
        if (i < e) {
            ds[j] = dst[i];
            ss[j] = src[i];
            atomicAdd(&hist[ds[j] >> BSHIFT], 1);
        } else {
            ds[j] = -1;
        }
    }
    __syncthreads();

    // reserve per-bucket space in this block's shard; then reuse hist as rank ctr
    for (int i = t; i < nb; i += 256) {
        int h = hist[i];
        base[i] = (h > 0) ? atomicAdd(&bcur2[i * 8 + x], h) : 0;
        hist[i] = 0;
    }
    __syncthreads();

#pragma unroll
    for (int j = 0; j < P1_EPT; j++) {
        if (ds[j] >= 0) {
            int b = ds[j] >> BSHIFT;
            int r = atomicAdd(&hist[b], 1);
            int slot = base[b] + r;
            if (slot < CELL_CAP) {
                cells[(size_t)(b * 8 + x) * CELL_CAP + slot] = make_int2(ss[j], ds[j]);
            } else {
                int sp = atomicAdd(spillCnt, 1);
                spill[sp] = make_int2(ss[j], ds[j]);
            }
        }
    }
}

// Per-node degree from cells (LDS atomics) + dinv.
__global__ __launch_bounds__(256) void count_cells(const int* __restrict__ bcur2,
                                                   const int2* __restrict__ cells,
                                                   const int2* __restrict__ spill,
                                                   const int* __restrict__ spillCnt,
                                                   int* __restrict__ counts,
                                                   float* __restrict__ dinv,
                                                   int n) {
    __shared__ int cnt[BWIDTH];
    int b = blockIdx.x;
    int t = threadIdx.x;
    int nodeBase = b << BSHIFT;
    if (t < BWIDTH) cnt[t] = 0;
    __syncthreads();
    for (int x = 0; x < 8; x++) {
        int c = bcur2[b * 8 + x];
        if (c > CELL_CAP) c = CELL_CAP;
        const int2* cp = cells + (size_t)(b * 8 + x) * CELL_CAP;
        for (int s = t; s < c; s += 256) {
            atomicAdd(&cnt[cp[s].y - nodeBase], 1);
        }
    }
    int sc = *spillCnt;
    for (int s = t; s < sc; s += 256) {
        int d = spill[s].y;
        if ((d >> BSHIFT) == b) atomicAdd(&cnt[d - nodeBase], 1);
    }
    __syncthreads();
    if (t < BWIDTH) {
        int node = nodeBase + t;
        if (node < n) {
            int deg = cnt[t] + 1;                  // +1 self loop
            counts[node] = deg;
            dinv[node] = 1.0f / sqrtf((float)deg);
        }
    }
}

// Scans use PADDED edge-slot counts: pad(deg) = (deg+3)&~3, deg = counts-1.
__global__ __launch_bounds__(256) void scan_phase1(const int* __restrict__ counts,
                                                   int* __restrict__ blockSums, int n) {
    __shared__ int red[256];
    int t = threadIdx.x;
    int base = blockIdx.x * 1024 + t * 4;
    int s = 0;
    if (base + 3 < n) {
        int4 v = *(const int4*)(counts + base);
        s = ((v.x + 2) & ~3) + ((v.y + 2) & ~3) + ((v.z + 2) & ~3) + ((v.w + 2) & ~3);
    } else {
        for (int j = 0; j < 4; j++) if (base + j < n) s += (counts[base + j] + 2) & ~3;
    }
    red[t] = s;
    __syncthreads();
    for (int off = 128; off > 0; off >>= 1) {
        if (t < off) red[t] += red[t + off];
        __syncthreads();
    }
    if (t == 0) blockSums[blockIdx.x] = red[0];
}

__global__ __launch_bounds__(1024) void scan_phase2(int* __restrict__ blockSums, int nb) {
    __shared__ int sh[1024];
    int t = threadIdx.x;
    sh[t] = (t < nb) ? blockSums[t] : 0;
    __syncthreads();
    for (int off = 1; off < 1024; off <<= 1) {
        int v = (t >= off) ? sh[t - off] : 0;
        __syncthreads();
        sh[t] += v;
        __syncthreads();
    }
    if (t < nb) blockSums[t] = (t == 0) ? 0 : sh[t - 1];
}

__global__ __launch_bounds__(256) void scan_phase3(const int* __restrict__ counts,
                                                   const int* __restrict__ blockSums,
                                                   int* __restrict__ offsets, int n) {
    __shared__ int red[256];
    int t = threadIdx.x;
    int base = blockIdx.x * 1024 + t * 4;
    int c[4];
#pragma unroll
    for (int j = 0; j < 4; j++) c[j] = (base + j < n) ? ((counts[base + j] + 2) & ~3) : 0;
    int s = c[0] + c[1] + c[2] + c[3];
    red[t] = s;
    __syncthreads();
    for (int off = 1; off < 256; off <<= 1) {
        int v = (t >= off) ? red[t - off] : 0;
        __syncthreads();
        red[t] += v;
        __syncthreads();
    }
    int prefix = blockSums[blockIdx.x] + ((t == 0) ? 0 : red[t - 1]);
#pragma unroll
    for (int j = 0; j < 4; j++) {
        if (base + j < n) offsets[base + j] = prefix;
        prefix += c[j];
        if (base + j == n - 1) offsets[n] = prefix;
    }
}

// Pass 2: cells -> srcSorted via LDS ranks. No global atomics.
// Fused pad-fill: cur[] holds each node's placed-edge count afterwards.
__global__ __launch_bounds__(256) void pass2_scatter(const int* __restrict__ bcur2,
                                                     const int2* __restrict__ cells,
                                                     const int2* __restrict__ spill,
                                                     const int* __restrict__ spillCnt,
                                                     const int* __restrict__ offsets,
                                                     int* __restrict__ srcSorted, int n) {
    __shared__ int cur[BWIDTH];
    int b = blockIdx.x;
    int t = threadIdx.x;
    int nodeBase = b << BSHIFT;
    if (t < BWIDTH) cur[t] = 0;
    __syncthreads();
    for (int x = 0; x < 8; x++) {
        int c = bcur2[b * 8 + x];
        if (c > CELL_CAP) c = CELL_CAP;
        const int2* cp = cells + (size_t)(b * 8 + x) * CELL_CAP;
        for (int s = t; s < c; s += 256) {
            int2 p = cp[s];
            int r = atomicAdd(&cur[p.y - nodeBase], 1);
            srcSorted[offsets[p.y] + r] = p.x;
        }
    }
    int sc = *spillCnt;
    for (int s = t; s < sc; s += 256) {
        int2 p = spill[s];
        if ((p.y >> BSHIFT) == b) {
            int r = atomicAdd(&cur[p.y - nodeBase], 1);
            srcSorted[offsets[p.y] + r] = p.x;
        }
    }
    __syncthreads();
    if (t < BWIDTH) {
        int node = nodeBase + t;
        if (node < n) {
            int beg = offsets[node] + cur[t];
            int end = offsets[node + 1];
            for (int k = beg; k < end; k++) srcSorted[k] = n;   // dummy -> zero row
        }
    }
}

// ---------------- weight prep ----------------

__device__ inline void split_bf16(float f, unsigned short& h, unsigned short& l) {
    unsigned u = __float_as_uint(f);
    unsigned hr = (u + 0x7FFFu + ((u >> 16) & 1u)) >> 16;    // RNE to bf16
    h = (unsigned short)hr;
    float r = f - __uint_as_float(hr << 16);
    unsigned v = __float_as_uint(r);
    unsigned lr = (v + 0x7FFFu + ((v >> 16) & 1u)) >> 16;
    l = (unsigned short)lr;
}

// Pack W[128][128] into 16x16x32 B-fragment layout, split into hi/lo bf16.
// Also (first call) zeroes h' row N (the dummy gather target).
__global__ __launch_bounds__(256) void prep_wfrag(const float* __restrict__ W,
                                                  short* __restrict__ wh,
                                                  short* __restrict__ wl,
                                                  __half* __restrict__ zrow) {
    if (zrow != nullptr && blockIdx.x == 0 && threadIdx.x < 64) {
        ((__half2*)zrow)[threadIdx.x] = __floats2half2_rn(0.f, 0.f);
    }
    int idx = blockIdx.x * 256 + threadIdx.x;   // 0..16383
    int j    = idx & 7;
    int lane = (idx >> 3) & 63;
    int c    = (idx >> 9) & 3;
    int t    = idx >> 11;
    int quad = lane >> 4;
    int n = (t << 4) | (lane & 15);
    int k = (c << 5) + (quad << 3) + j;
    unsigned short h, l;
    split_bf16(W[k * 128 + n], h, l);
    wh[idx] = (short)h;
    wl[idx] = (short)l;
}

// fp16-split weights for the f16-MFMA path: wh = f16(W), wl = f16((W-wh)*2048).
__global__ __launch_bounds__(256) void prep_wfrag16(const float* __restrict__ W,
                                                    _Float16* __restrict__ wh,
                                                    _Float16* __restrict__ wl) {
    int idx = blockIdx.x * 256 + threadIdx.x;   // 0..16383
    int j    = idx & 7;
    int lane = (idx >> 3) & 63;
    int c    = (idx >> 9) & 3;
    int t    = idx >> 11;
    int quad = lane >> 4;
    int n = (t << 4) | (lane & 15);
    int k = (c << 5) + (quad << 3) + j;
    float v = W[k * 128 + n];
    _Float16 h = (_Float16)v;
    _Float16 l = (_Float16)((v - (float)h) * 2048.0f);
    wh[idx] = h;
    wl[idx] = l;
}

// ---------------- GEMM: [M,128] @ [128,128], fp32 A, bf16-split MFMA --------
// Output pre-scaled by dinv[row], stored fp16. (layer 1 only)

#define GEMM_GX 512

__global__ __launch_bounds__(256) void gemm_mfma(const float* __restrict__ A,
                                                 const short* __restrict__ wh,
                                                 const short* __restrict__ wl,
                                                 const float* __restrict__ dinv,
                                                 __half* __restrict__ C, int M) {
    int wv   = threadIdx.x >> 6;
    int lane = threadIdx.x & 63;
    int quad = lane >> 4;
    int mm   = lane & 15;
    int tbase = blockIdx.y * 4;

    s16x8 whf[4][4], wlf[4][4];
#pragma unroll
    for (int tt = 0; tt < 4; tt++)
#pragma unroll
        for (int c = 0; c < 4; c++) {
            int base = ((((tbase + tt) << 2) + c) << 6 | lane) << 3;
            whf[tt][c] = *(const s16x8*)(wh + base);
            wlf[tt][c] = *(const s16x8*)(wl + base);
        }

    int nStrips = M >> 4;
    for (int s = blockIdx.x * 4 + wv; s < nStrips; s += GEMM_GX * 4) {
        const float* ap = A + (size_t)((s << 4) + mm) * 128 + (quad << 3);
        f32x4 acc[4];
#pragma unroll
        for (int tt = 0; tt < 4; tt++) acc[tt] = (f32x4){0.f, 0.f, 0.f, 0.f};

#pragma unroll
        for (int c = 0; c < 4; c++) {
            float av[8];
            *(float4*)&av[0] = *(const float4*)(ap + (c << 5));
            *(float4*)&av[4] = *(const float4*)(ap + (c << 5) + 4);
            union { s16x8 v; unsigned short u[8]; } ah, al;
#pragma unroll
            for (int j = 0; j < 8; j++) split_bf16(av[j], ah.u[j], al.u[j]);
#pragma unroll
            for (int tt = 0; tt < 4; tt++) {
                acc[tt] = __builtin_amdgcn_mfma_f32_16x16x32_bf16(ah.v, whf[tt][c], acc[tt], 0, 0, 0);
                acc[tt] = __builtin_amdgcn_mfma_f32_16x16x32_bf16(ah.v, wlf[tt][c], acc[tt], 0, 0, 0);
                acc[tt] = __builtin_amdgcn_mfma_f32_16x16x32_bf16(al.v, whf[tt][c], acc[tt], 0, 0, 0);
                acc[tt] = __builtin_amdgcn_mfma_f32_16x16x32_bf16(al.v, wlf[tt][c], acc[tt], 0, 0, 0);
            }
        }
        // C/D layout: col = lane&15, row = quad*4 + reg
        int rbase = (s << 4) + (quad << 2);
        float dv[4];
#pragma unroll
        for (int r = 0; r < 4; r++) dv[r] = dinv[rbase + r];
        __half* cp = C + (size_t)rbase * 128 + (tbase << 4) + mm;
#pragma unroll
        for (int tt = 0; tt < 4; tt++) {
#pragma unroll
            for (int r = 0; r < 4; r++) {
                cp[(size_t)r * 128 + (tt << 4)] = __float2half(acc[tt][r] * dv[r]);
            }
        }
    }
}

// ---------------- GEMM: [M,128] @ [128,128], fp16 A, direct f16 MFMA --------
// A already fp16: no split, 2 MFMA per frag (wh + wl*2^-11). (layers 2,3)

__global__ __launch_bounds__(256) void gemm_mfma_f16(const __half* __restrict__ A,
                                                     const _Float16* __restrict__ wh,
                                                     const _Float16* __restrict__ wl,
                                                     const float* __restrict__ dinv,
                                                     __half* __restrict__ C, int M) {
    int wv   = threadIdx.x >> 6;
    int lane = threadIdx.x & 63;
    int quad = lane >> 4;
    int mm   = lane & 15;
    int tbase = blockIdx.y * 4;

    f16x8 whf[4][4], wlf[4][4];
#pragma unroll
    for (int tt = 0; tt < 4; tt++)
#pragma unroll
        for (int c = 0; c < 4; c++) {
            int base = ((((tbase + tt) << 2) + c) << 6 | lane) << 3;
            whf[tt][c] = *(const f16x8*)(wh + base);
            wlf[tt][c] = *(const f16x8*)(wl + base);
        }

    int nStrips = M >> 4;
    for (int s = blockIdx.x * 4 + wv; s < nStrips; s += GEMM_GX * 4) {
        const _Float16* ap = (const _Float16*)A + (size_t)((s << 4) + mm) * 128 + (quad << 3);
        f32x4 acch[4], accl[4];
#pragma unroll
        for (int tt = 0; tt < 4; tt++) {
            acch[tt] = (f32x4){0.f, 0.f, 0.f, 0.f};
            accl[tt] = (f32x4){0.f, 0.f, 0.f, 0.f};
        }

#pragma unroll
        for (int c = 0; c < 4; c++) {
            f16x8 av = *(const f16x8*)(ap + (c << 5));
#pragma unroll
            for (int tt = 0; tt < 4; tt++) {
                acch[tt] = __builtin_amdgcn_mfma_f32_16x16x32_f16(av, whf[tt][c], acch[tt], 0, 0, 0);
                accl[tt] = __builtin_amdgcn_mfma_f32_16x16x32_f16(av, wlf[tt][c], accl[tt], 0, 0, 0);
            }
        }
        int rbase = (s << 4) + (quad << 2);
        float dv[4];
#pragma unroll
        for (int r = 0; r < 4; r++) dv[r] = dinv[rbase + r];
        __half* cp = C + (size_t)rbase * 128 + (tbase << 4) + mm;
#pragma unroll
        for (int tt = 0; tt < 4; tt++) {
#pragma unroll
            for (int r = 0; r < 4; r++) {
                float v = acch[tt][r] + accl[tt][r] * (1.0f / 2048.0f);
                cp[(size_t)r * 128 + (tt << 4)] = __float2half(v * dv[r]);
            }
        }
    }
}

// ---------------- GEMM: [M,128] @ [128,40] -> fp16 [M+1,40], dinv-scaled ----

__global__ __launch_bounds__(320) void gemm_f32_40(const float* __restrict__ A,
                                                   const float* __restrict__ B,
                                                   const float* __restrict__ dinv,
                                                   __half* __restrict__ C, int M) {
    __shared__ float Ws[128][40];
    __shared__ float Xs[32][132];
    int t = threadIdx.x;
    int block_row = blockIdx.x * 32;

    for (int i = t; i < 128 * 40; i += 320) ((float*)Ws)[i] = B[i];
    for (int idx = t; idx < 1024; idx += 320) {
        int row = idx >> 5;
        int k4  = (idx & 31) << 2;
        int gr = block_row + row; if (gr >= M) gr = M - 1;
        float4 v = *(const float4*)(A + (size_t)gr * 128 + k4);
        *(float4*)&Xs[row][k4] = v;
    }
    __syncthreads();

    int r  = t / 10;
    int c0 = (t % 10) * 4;
    float4 acc = make_float4(0.f, 0.f, 0.f, 0.f);
    for (int k = 0; k < 128; k += 4) {
        float4 xv = *(const float4*)&Xs[r][k];
#pragma unroll
        for (int j = 0; j < 4; j++) {
            float xj = (j == 0) ? xv.x : (j == 1) ? xv.y : (j == 2) ? xv.z : xv.w;
            float4 wv = *(const float4*)&Ws[k + j][c0];
            acc.x += xj * wv.x; acc.y += xj * wv.y;
            acc.z += xj * wv.z; acc.w += xj * wv.w;
        }
    }
    int gr = block_row + r;
    if (gr < M) {
        float dv = dinv[gr];
        __half2* p = (__half2*)(C + (size_t)gr * 40 + c0);
        p[0] = __floats2half2_rn(dv * acc.x, dv * acc.y);
        p[1] = __floats2half2_rn(dv * acc.z, dv * acc.w);
    } else if (gr == M) {   // dummy row for padded gathers
        __half2* p = (__half2*)(C + (size_t)gr * 40 + c0);
        p[0] = __floats2half2_rn(0.f, 0.f);
        p[1] = __floats2half2_rn(0.f, 0.f);
    }
}

// ---------------- CSR aggregation ----------------
// h rows are h'[i] = dinv[i]*h[i] (fp16, row n = 0). CSR rows padded to x4.
// out[i] = relu?( dinv[i] * sum(h' over {i} u nbrs) + b )

__device__ inline f32x2 h2f(__half2 v) {
    float2 t = __half22float2(v);
    return (f32x2){t.x, t.y};
}

// NF=128 sliced: slice = blockIdx.x & 3 (32 features = 64B of each 256B row);
// with round-robin block->XCD dispatch, slice s lives on XCDs {s, s+4} so each
// L2 caches only its 6.4MB slice column. Wave = 4 sub-nodes x 16 lanes.
template <bool RELU, typename OT>
__global__ __launch_bounds__(256) void agg128_sliced(const __half* __restrict__ h,
                                                     const float* __restrict__ dinv,
                                                     const int* __restrict__ offsets,
                                                     const int* __restrict__ srcSorted,
                                                     const float* __restrict__ bias,
                                                     OT* __restrict__ out, int n) {
    int slice = blockIdx.x & 3;
    int nodeBase = (blockIdx.x >> 2) << 4;     // 16 nodes per block
    int wave = threadIdx.x >> 6;
    int lane = threadIdx.x & 63;
    int sub  = lane >> 4;                      // 0..3 sub-node
    int fl   = lane & 15;                      // feature pair within slice
    int node = nodeBase + (wave << 2) + sub;
    bool on = (node < n);

    const char* hb = (const char*)h;
    unsigned fb = ((unsigned)slice << 6) + ((unsigned)fl << 2);   // byte off in 256B row
    int f = (slice << 5) + (fl << 1);
    float2 bv = *(const float2*)(bias + f);    // f < 128 always

    float di = on ? dinv[node] : 0.f;
    int idx = on ? offsets[node] : 0;
    int end = on ? offsets[node + 1] : 0;

    f32x2 z = (f32x2){0.f, 0.f};
    f32x2 a0 = z, a1 = z, a2 = z, a3 = z;
    if (on) a0 = h2f(*(const __half2*)(hb + (unsigned)node * 256u + fb));

    while (__any(idx + 8 <= end)) {
        bool c = (idx + 8 <= end);
        if (c) {
            int4 sA = *(const int4*)(srcSorted + idx);
            int4 sB = *(const int4*)(srcSorted + idx + 4);
            a0 += h2f(*(const __half2*)(hb + (unsigned)sA.x * 256u + fb));
            a1 += h2f(*(const __half2*)(hb + (unsigned)sA.y * 256u + fb));
            a2 += h2f(*(const __half2*)(hb + (unsigned)sA.z * 256u + fb));
            a3 += h2f(*(const __half2*)(hb + (unsigned)sA.w * 256u + fb));
            a0 += h2f(*(const __half2*)(hb + (unsigned)sB.x * 256u + fb));
            a1 += h2f(*(const __half2*)(hb + (unsigned)sB.y * 256u + fb));
            a2 += h2f(*(const __half2*)(hb + (unsigned)sB.z * 256u + fb));
            a3 += h2f(*(const __half2*)(hb + (unsigned)sB.w * 256u + fb));
            idx += 8;
        }
    }
    if (idx + 4 <= end) {   // padded remainder is 0 or 4
        int4 sA = *(const int4*)(srcSorted + idx);
        a0 += h2f(*(const __half2*)(hb + (unsigned)sA.x * 256u + fb));
        a1 += h2f(*(const __half2*)(hb + (unsigned)sA.y * 256u + fb));
        a2 += h2f(*(const __half2*)(hb + (unsigned)sA.z * 256u + fb));
        a3 += h2f(*(const __half2*)(hb + (unsigned)sA.w * 256u + fb));
    }

    if (on) {
        f32x2 s = (a0 + a1) + (a2 + a3);
        float ox = di * s.x + bv.x;
        float oy = di * s.y + bv.y;
        if (RELU) { ox = fmaxf(ox, 0.f); oy = fmaxf(oy, 0.f); }
        if constexpr (sizeof(OT) == 2) {
            *(__half2*)(out + (size_t)node * 128 + f) = __floats2half2_rn(ox, oy);
        } else {
            *(float2*)(out + (size_t)node * 128 + f) = make_float2(ox, oy);
        }
    }
}

// NF=40: three nodes per wave (lanes 0-19 / 20-39 / 40-59), fp32 out, no relu.
__global__ __launch_bounds__(256) void agg40_tri(const __half* __restrict__ h,
                                                 const float* __restrict__ dinv,
                                                 const int* __restrict__ offsets,
                                                 const int* __restrict__ srcSorted,
                                                 const float* __restrict__ bias,
                                                 float* __restrict__ out, int n) {
    int wave = threadIdx.x >> 6;
    int lane = threadIdx.x & 63;
    unsigned sub = (unsigned)lane / 20u;       // 0..3 (3 = idle lanes 60-63)
    int fi = lane - (int)sub * 20;
    bool act = (sub < 3u);
    int f = fi * 2;
    unsigned fb = (unsigned)fi * 4u;           // byte offset in 80B row
    const char* hb = (const char*)h;
    float bx = act ? bias[f] : 0.f;
    float by = act ? bias[f + 1] : 0.f;
    int ntri = (n + 2) / 3;

    for (int p = blockIdx.x * 4 + wave; p < ntri; p += gridDim.x * 4) {
        int node = p * 3 + (int)sub;
        bool on = act && (node < n);
        float di = on ? dinv[node] : 0.f;
        int idx = on ? offsets[node] : 0;
        int end = on ? offsets[node + 1] : 0;

        f32x2 z = (f32x2){0.f, 0.f};
        f32x2 a0 = z, a1 = z, a2 = z, a3 = z;
        if (on) a0 = h2f(*(const __half2*)(hb + (unsigned)node * 80u + fb));

        while (__any(idx + 8 <= end)) {
            bool c = (idx + 8 <= end);
            if (c) {
                int4 sA = *(const int4*)(srcSorted + idx);
                int4 sB = *(const int4*)(srcSorted + idx + 4);
                a0 += h2f(*(const __half2*)(hb + (unsigned)sA.x * 80u + fb));
                a1 += h2f(*(const __half2*)(hb + (unsigned)sA.y * 80u + fb));
                a2 += h2f(*(const __half2*)(hb + (unsigned)sA.z * 80u + fb));
                a3 += h2f(*(const __half2*)(hb + (unsigned)sA.w * 80u + fb));
                a0 += h2f(*(const __half2*)(hb + (unsigned)sB.x * 80u + fb));
                a1 += h2f(*(const __half2*)(hb + (unsigned)sB.y * 80u + fb));
                a2 += h2f(*(const __half2*)(hb + (unsigned)sB.z * 80u + fb));
                a3 += h2f(*(const __half2*)(hb + (unsigned)sB.w * 80u + fb));
                idx += 8;
            }
        }
        if (idx + 4 <= end) {   // padded remainder is 0 or 4
            int4 sA = *(const int4*)(srcSorted + idx);
            a0 += h2f(*(const __half2*)(hb + (unsigned)sA.x * 80u + fb));
            a1 += h2f(*(const __half2*)(hb + (unsigned)sA.y * 80u + fb));
            a2 += h2f(*(const __half2*)(hb + (unsigned)sA.z * 80u + fb));
            a3 += h2f(*(const __half2*)(hb + (unsigned)sA.w * 80u + fb));
        }

        if (on) {
            f32x2 s = (a0 + a1) + (a2 + a3);
            float ox = di * s.x + bx;
            float oy = di * s.y + by;
            *(float2*)(out + (size_t)node * 40 + f) = make_float2(ox, oy);
        }
    }
}

// ---------------- orchestration ----------------

extern "C" void kernel_launch(void* const* d_in, const int* in_sizes, int n_in,
                              void* d_out, int out_size, void* d_ws, size_t ws_size,
                              hipStream_t stream) {
    const float* x  = (const float*)d_in[0];
    const int* edge = (const int*)d_in[1];
    const float* W1 = (const float*)d_in[2]; const float* b1 = (const float*)d_in[3];
    const float* W2 = (const float*)d_in[4]; const float* b2 = (const float*)d_in[5];
    const float* W3 = (const float*)d_in[6]; const float* b3 = (const float*)d_in[7];
    const float* W4 = (const float*)d_in[8]; const float* b4 = (const float*)d_in[9];

    const int N = in_sizes[0] / 128;      // 100000
    const int E = in_sizes[1] / 2;        // 1600000
    const int* src = edge;
    const int* dst = edge + E;

    float* out_final = (float*)d_out;                    // [N,40]
    float* x_latent  = (float*)d_out + (size_t)N * 40;   // [N,128]

    const int nbk = (N + BWIDTH - 1) >> BSHIFT;          // 782 buckets (<=1024 required)

    // workspace carve-up
    char* w = (char*)d_ws;
    int* counts    = (int*)w;  w += (size_t)N * 4;
    int* offsets   = (int*)w;  w += (size_t)(N + 4) * 4;
    float* dinv    = (float*)w; w += (size_t)N * 4;
    int* srcSorted = (int*)w;  w += (size_t)(E + 4 * N) * 4;   // padded CSR
    int* blockSums = (int*)w;  w += (size_t)1024 * 4;
    int* bcur2     = (int*)w;  w += (size_t)8448 * 4;    // nbk*8 = 6256, padded
    int* spillCnt  = (int*)w;  w += (size_t)64 * 4;      // contiguous with bcur2
    short* wfrag   = (short*)w;    w += (size_t)2 * 16384 * 2;   // layer1 {hi,lo} bf16
    _Float16* wf16 = (_Float16*)w; w += (size_t)4 * 16384 * 2;   // layers 2,3 {hi,lo} f16
    w = (char*)(((uintptr_t)w + 255) & ~(uintptr_t)255);
    __half* hA   = (__half*)w; w += (size_t)(N + 1) * 128 * 2;   // h' (pre-scaled), row N = 0
    __half* hB16 = (__half*)w; w += (size_t)N * 128 * 2;         // fp16 agg out (layers 1-2)

    // cells + spill alias hA+hB16 (first written only after CSR build):
    //   cells: nbk*8*CELL_CAP*8B = 25.6MB, spill: E*8B = 12.8MB  (<= 51.2MB)
    int2* cells = (int2*)hA;
    int2* spill = cells + (size_t)nbk * 8 * CELL_CAP;

    short* wh1 = wfrag;            short* wl1 = wfrag + 16384;
    _Float16* wh2 = wf16;          _Float16* wl2 = wf16 + 16384;
    _Float16* wh3 = wf16 + 32768;  _Float16* wl3 = wf16 + 49152;

    int nb = (N + 1023) / 1024;   // 98 (scan blocks)
    int p1b = (E + P1_CHUNK - 1) / P1_CHUNK;   // 391

    hipMemsetAsync(bcur2, 0, (size_t)(8448 + 64) * 4, stream);   // bcur2 + spillCnt
    pass1_bucket<<<p1b, 256, 0, stream>>>(src, dst, bcur2, cells, spill, spillCnt, nbk, E);
    count_cells<<<nbk, 256, 0, stream>>>(bcur2, cells, spill, spillCnt, counts, dinv, N);
    scan_phase1<<<nb, 256, 0, stream>>>(counts, blockSums, N);
    scan_phase2<<<1, 1024, 0, stream>>>(blockSums, nb);
    scan_phase3<<<nb, 256, 0, stream>>>(counts, blockSums, offsets, N);
    pass2_scatter<<<nbk, 256, 0, stream>>>(bcur2, cells, spill, spillCnt, offsets, srcSorted, N);

    prep_wfrag<<<64, 256, 0, stream>>>(W1, wh1, wl1, hA + (size_t)N * 128);
    prep_wfrag16<<<64, 256, 0, stream>>>(W2, wh2, wl2);
    prep_wfrag16<<<64, 256, 0, stream>>>(W3, wh3, wl3);

    dim3 gGemm(GEMM_GX, 2);
    int gAggS = 4 * ((N + 15) / 16);   // 25000 blocks: 4 slices x node groups

    gemm_mfma<<<gGemm, 256, 0, stream>>>(x, wh1, wl1, dinv, hA, N);
    agg128_sliced<true, __half><<<gAggS, 256, 0, stream>>>(hA, dinv, offsets, srcSorted, b1, hB16, N);
    gemm_mfma_f16<<<gGemm, 256, 0, stream>>>(hB16, wh2, wl2, dinv, hA, N);
    agg128_sliced<true, __half><<<gAggS, 256, 0, stream>>>(hA, dinv, offsets, srcSorted, b2, hB16, N);
    gemm_mfma_f16<<<gGemm, 256, 0, stream>>>(hB16, wh3, wl3, dinv, hA, N);
    agg128_sliced<true, float><<<gAggS, 256, 0, stream>>>(hA, dinv, offsets, srcSorted, b3, x_latent, N);
    gemm_f32_40<<<(N + 1 + 31) / 32, 320, 0, stream>>>(x_latent, W4, dinv, hA, N);
    agg40_tri<<<2048, 256, 0, stream>>>(hA, dinv, offsets, srcSorted, b4, out_final, N);
}

// Round 7
// 450.891 us; speedup vs baseline: 1.3417x; 1.3417x over previous
//
#include <hip/hip_runtime.h>
#include <hip/hip_bf16.h>
#include <hip/hip_fp16.h>

// GCN: 4 layers. N=100000, E=1600000, F=H=128, C=40. fp32 in/out.
// R12 changes vs R11:
//  - REVERT agg to R10 gather structure (R11 slicing: FETCH 192->327MB,
//    line-granularity waste + no real blockIdx->XCD pinning).
//  - FUSE agg_k + gemm_{k+1}: block = 16 nodes; gather phase (4 waves x 4
//    nodes, R8 loop) -> LDS (stride 136, conflict-free frags) -> f16 MFMA
//    phase (weights streamed from L2, 2 tiles/wave). Eliminates standalone
//    gemm2/gemm3/gemm40 dispatches (~55us serial) + intermediate h traffic.
//  - Final layer fused too: fused40 writes x_latent (fp32) + h4' (fp16
//    [N+1,40], W4 fp16-split 48-col frag). agg40_tri unchanged.

#define N_NODES 100000
#define N_EDGES 1600000

#define BSHIFT 7
#define BWIDTH 128
#define CELL_CAP 512
#define P1_EPT 16
#define P1_CHUNK 4096

typedef short s16x8 __attribute__((ext_vector_type(8)));
typedef _Float16 f16x8 __attribute__((ext_vector_type(8)));
typedef float f32x4 __attribute__((ext_vector_type(4)));
typedef float f32x2 __attribute__((ext_vector_type(2)));

// ---------------- CSR build (bucketed) ----------------

__global__ __launch_bounds__(256) void pass1_bucket(const int* __restrict__ src,
                                                    const int* __restrict__ dst,
                                                    int* __restrict__ bcur2,
                                                    int2* __restrict__ cells,
                                                    int2* __restrict__ spill,
                                                    int* __restrict__ spillCnt,
                                                    int nb, int e) {
    __shared__ int hist[1024];
    __shared__ int base[1024];
    int t = threadIdx.x;
    int x = blockIdx.x & 7;
    int e0 = blockIdx.x * P1_CHUNK;

    for (int i = t; i < nb; i += 256) hist[i] = 0;
    __syncthreads();

    int ds[P1_EPT], ss[P1_EPT];
#pragma unroll
    for (int j = 0; j < P1_EPT; j++) {
        int i = e0 + j * 256 + t;
        if (i < e) {
            ds[j] = dst[i];
            ss[j] = src[i];
            atomicAdd(&hist[ds[j] >> BSHIFT], 1);
        } else {
            ds[j] = -1;
        }
    }
    __syncthreads();

    for (int i = t; i < nb; i += 256) {
        int h = hist[i];
        base[i] = (h > 0) ? atomicAdd(&bcur2[i * 8 + x], h) : 0;
        hist[i] = 0;
    }
    __syncthreads();

#pragma unroll
    for (int j = 0; j < P1_EPT; j++) {
        if (ds[j] >= 0) {
            int b = ds[j] >> BSHIFT;
            int r = atomicAdd(&hist[b], 1);
            int slot = base[b] + r;
            if (slot < CELL_CAP) {
                cells[(size_t)(b * 8 + x) * CELL_CAP + slot] = make_int2(ss[j], ds[j]);
            } else {
                int sp = atomicAdd(spillCnt, 1);
                spill[sp] = make_int2(ss[j], ds[j]);
            }
        }
    }
}

__global__ __launch_bounds__(256) void count_cells(const int* __restrict__ bcur2,
                                                   const int2* __restrict__ cells,
                                                   const int2* __restrict__ spill,
                                                   const int* __restrict__ spillCnt,
                                                   int* __restrict__ counts,
                                                   float* __restrict__ dinv,
                                                   int n) {
    __shared__ int cnt[BWIDTH];
    int b = blockIdx.x;
    int t = threadIdx.x;
    int nodeBase = b << BSHIFT;
    if (t < BWIDTH) cnt[t] = 0;
    __syncthreads();
    for (int x = 0; x < 8; x++) {
        int c = bcur2[b * 8 + x];
        if (c > CELL_CAP) c = CELL_CAP;
        const int2* cp = cells + (size_t)(b * 8 + x) * CELL_CAP;
        for (int s = t; s < c; s += 256) {
            atomicAdd(&cnt[cp[s].y - nodeBase], 1);
        }
    }
    int sc = *spillCnt;
    for (int s = t; s < sc; s += 256) {
        int d = spill[s].y;
        if ((d >> BSHIFT) == b) atomicAdd(&cnt[d - nodeBase], 1);
    }
    __syncthreads();
    if (t < BWIDTH) {
        int node = nodeBase + t;
        if (node < n) {
            int deg = cnt[t] + 1;
            counts[node] = deg;
            dinv[node] = 1.0f / sqrtf((float)deg);
        }
    }
}

__global__ __launch_bounds__(256) void scan_phase1(const int* __restrict__ counts,
                                                   int* __restrict__ blockSums, int n) {
    __shared__ int red[256];
    int t = threadIdx.x;
    int base = blockIdx.x * 1024 + t * 4;
    int s = 0;
    if (base + 3 < n) {
        int4 v = *(const int4*)(counts + base);
        s = ((v.x + 2) & ~3) + ((v.y + 2) & ~3) + ((v.z + 2) & ~3) + ((v.w + 2) & ~3);
    } else {
        for (int j = 0; j < 4; j++) if (base + j < n) s += (counts[base + j] + 2) & ~3;
    }
    red[t] = s;
    __syncthreads();
    for (int off = 128; off > 0; off >>= 1) {
        if (t < off) red[t] += red[t + off];
        __syncthreads();
    }
    if (t == 0) blockSums[blockIdx.x] = red[0];
}

__global__ __launch_bounds__(1024) void scan_phase2(int* __restrict__ blockSums, int nb) {
    __shared__ int sh[1024];
    int t = threadIdx.x;
    sh[t] = (t < nb) ? blockSums[t] : 0;
    __syncthreads();
    for (int off = 1; off < 1024; off <<= 1) {
        int v = (t >= off) ? sh[t - off] : 0;
        __syncthreads();
        sh[t] += v;
        __syncthreads();
    }
    if (t < nb) blockSums[t] = (t == 0) ? 0 : sh[t - 1];
}

__global__ __launch_bounds__(256) void scan_phase3(const int* __restrict__ counts,
                                                   const int* __restrict__ blockSums,
                                                   int* __restrict__ offsets, int n) {
    __shared__ int red[256];
    int t = threadIdx.x;
    int base = blockIdx.x * 1024 + t * 4;
    int c[4];
#pragma unroll
    for (int j = 0; j < 4; j++) c[j] = (base + j < n) ? ((counts[base + j] + 2) & ~3) : 0;
    int s = c[0] + c[1] + c[2] + c[3];
    red[t] = s;
    __syncthreads();
    for (int off = 1; off < 256; off <<= 1) {
        int v = (t >= off) ? red[t - off] : 0;
        __syncthreads();
        red[t] += v;
        __syncthreads();
    }
    int prefix = blockSums[blockIdx.x] + ((t == 0) ? 0 : red[t - 1]);
#pragma unroll
    for (int j = 0; j < 4; j++) {
        if (base + j < n) offsets[base + j] = prefix;
        prefix += c[j];
        if (base + j == n - 1) offsets[n] = prefix;
    }
}

__global__ __launch_bounds__(256) void pass2_scatter(const int* __restrict__ bcur2,
                                                     const int2* __restrict__ cells,
                                                     const int2* __restrict__ spill,
                                                     const int* __restrict__ spillCnt,
                                                     const int* __restrict__ offsets,
                                                     int* __restrict__ srcSorted, int n) {
    __shared__ int cur[BWIDTH];
    int b = blockIdx.x;
    int t = threadIdx.x;
    int nodeBase = b << BSHIFT;
    if (t < BWIDTH) cur[t] = 0;
    __syncthreads();
    for (int x = 0; x < 8; x++) {
        int c = bcur2[b * 8 + x];
        if (c > CELL_CAP) c = CELL_CAP;
        const int2* cp = cells + (size_t)(b * 8 + x) * CELL_CAP;
        for (int s = t; s < c; s += 256) {
            int2 p = cp[s];
            int r = atomicAdd(&cur[p.y - nodeBase], 1);
            srcSorted[offsets[p.y] + r] = p.x;
        }
    }
    int sc = *spillCnt;
    for (int s = t; s < sc; s += 256) {
        int2 p = spill[s];
        if ((p.y >> BSHIFT) == b) {
            int r = atomicAdd(&cur[p.y - nodeBase], 1);
            srcSorted[offsets[p.y] + r] = p.x;
        }
    }
    __syncthreads();
    if (t < BWIDTH) {
        int node = nodeBase + t;
        if (node < n) {
            int beg = offsets[node] + cur[t];
            int end = offsets[node + 1];
            for (int k = beg; k < end; k++) srcSorted[k] = n;
        }
    }
}

// ---------------- weight prep ----------------

__device__ inline void split_bf16(float f, unsigned short& h, unsigned short& l) {
    unsigned u = __float_as_uint(f);
    unsigned hr = (u + 0x7FFFu + ((u >> 16) & 1u)) >> 16;
    h = (unsigned short)hr;
    float r = f - __uint_as_float(hr << 16);
    unsigned v = __float_as_uint(r);
    unsigned lr = (v + 0x7FFFu + ((v >> 16) & 1u)) >> 16;
    l = (unsigned short)lr;
}

__global__ __launch_bounds__(256) void prep_wfrag(const float* __restrict__ W,
                                                  short* __restrict__ wh,
                                                  short* __restrict__ wl,
                                                  __half* __restrict__ zrow) {
    if (zrow != nullptr && blockIdx.x == 0 && threadIdx.x < 64) {
        ((__half2*)zrow)[threadIdx.x] = __floats2half2_rn(0.f, 0.f);
    }
    int idx = blockIdx.x * 256 + threadIdx.x;
    int j    = idx & 7;
    int lane = (idx >> 3) & 63;
    int c    = (idx >> 9) & 3;
    int t    = idx >> 11;
    int quad = lane >> 4;
    int n = (t << 4) | (lane & 15);
    int k = (c << 5) + (quad << 3) + j;
    unsigned short h, l;
    split_bf16(W[k * 128 + n], h, l);
    wh[idx] = (short)h;
    wl[idx] = (short)l;
}

__global__ __launch_bounds__(256) void prep_wfrag16(const float* __restrict__ W,
                                                    _Float16* __restrict__ wh,
                                                    _Float16* __restrict__ wl,
                                                    __half* __restrict__ zrow) {
    if (zrow != nullptr && blockIdx.x == 0 && threadIdx.x < 64) {
        ((__half2*)zrow)[threadIdx.x] = __floats2half2_rn(0.f, 0.f);
    }
    int idx = blockIdx.x * 256 + threadIdx.x;
    int j    = idx & 7;
    int lane = (idx >> 3) & 63;
    int c    = (idx >> 9) & 3;
    int t    = idx >> 11;
    int quad = lane >> 4;
    int n = (t << 4) | (lane & 15);
    int k = (c << 5) + (quad << 3) + j;
    float v = W[k * 128 + n];
    _Float16 h = (_Float16)v;
    _Float16 l = (_Float16)((v - (float)h) * 2048.0f);
    wh[idx] = h;
    wl[idx] = l;
}

// W4 [128,40] -> 48-col padded frag (3 tiles), fp16-split.
__global__ __launch_bounds__(256) void prep_wfrag40(const float* __restrict__ W,
                                                    _Float16* __restrict__ wh,
                                                    _Float16* __restrict__ wl) {
    int idx = blockIdx.x * 256 + threadIdx.x;   // 0..6143
    int j    = idx & 7;
    int lane = (idx >> 3) & 63;
    int c    = (idx >> 9) & 3;
    int t    = idx >> 11;                        // 0..2
    int quad = lane >> 4;
    int n = (t << 4) | (lane & 15);              // 0..47
    int k = (c << 5) + (quad << 3) + j;
    float v = (n < 40) ? W[k * 40 + n] : 0.f;
    _Float16 h = (_Float16)v;
    _Float16 l = (_Float16)((v - (float)h) * 2048.0f);
    wh[idx] = h;
    wl[idx] = l;
}

// ---------------- GEMM layer 1: fp32 A, bf16-split MFMA -> h1' fp16 --------

#define GEMM_GX 512

__global__ __launch_bounds__(256) void gemm_mfma(const float* __restrict__ A,
                                                 const short* __restrict__ wh,
                                                 const short* __restrict__ wl,
                                                 const float* __restrict__ dinv,
                                                 __half* __restrict__ C, int M) {
    int wv   = threadIdx.x >> 6;
    int lane = threadIdx.x & 63;
    int quad = lane >> 4;
    int mm   = lane & 15;
    int tbase = blockIdx.y * 4;

    s16x8 whf[4][4], wlf[4][4];
#pragma unroll
    for (int tt = 0; tt < 4; tt++)
#pragma unroll
        for (int c = 0; c < 4; c++) {
            int base = ((((tbase + tt) << 2) + c) << 6 | lane) << 3;
            whf[tt][c] = *(const s16x8*)(wh + base);
            wlf[tt][c] = *(const s16x8*)(wl + base);
        }

    int nStrips = M >> 4;
    for (int s = blockIdx.x * 4 + wv; s < nStrips; s += GEMM_GX * 4) {
        const float* ap = A + (size_t)((s << 4) + mm) * 128 + (quad << 3);
        f32x4 acc[4];
#pragma unroll
        for (int tt = 0; tt < 4; tt++) acc[tt] = (f32x4){0.f, 0.f, 0.f, 0.f};

#pragma unroll
        for (int c = 0; c < 4; c++) {
            float av[8];
            *(float4*)&av[0] = *(const float4*)(ap + (c << 5));
            *(float4*)&av[4] = *(const float4*)(ap + (c << 5) + 4);
            union { s16x8 v; unsigned short u[8]; } ah, al;
#pragma unroll
            for (int j = 0; j < 8; j++) split_bf16(av[j], ah.u[j], al.u[j]);
#pragma unroll
            for (int tt = 0; tt < 4; tt++) {
                acc[tt] = __builtin_amdgcn_mfma_f32_16x16x32_bf16(ah.v, whf[tt][c], acc[tt], 0, 0, 0);
                acc[tt] = __builtin_amdgcn_mfma_f32_16x16x32_bf16(ah.v, wlf[tt][c], acc[tt], 0, 0, 0);
                acc[tt] = __builtin_amdgcn_mfma_f32_16x16x32_bf16(al.v, whf[tt][c], acc[tt], 0, 0, 0);
                acc[tt] = __builtin_amdgcn_mfma_f32_16x16x32_bf16(al.v, wlf[tt][c], acc[tt], 0, 0, 0);
            }
        }
        int rbase = (s << 4) + (quad << 2);
        float dv[4];
#pragma unroll
        for (int r = 0; r < 4; r++) dv[r] = dinv[rbase + r];
        __half* cp = C + (size_t)rbase * 128 + (tbase << 4) + mm;
#pragma unroll
        for (int tt = 0; tt < 4; tt++) {
#pragma unroll
            for (int r = 0; r < 4; r++) {
                cp[(size_t)r * 128 + (tt << 4)] = __float2half(acc[tt][r] * dv[r]);
            }
        }
    }
}

// ---------------- fused agg + gemm ----------------
// Gather phase (R8 structure): wave w reduces nodes strip*16 + w*4 .. +3,
// result a = relu(dinv*S + b) staged in LDS fp16 (stride 136: 16B-aligned,
// conflict-free b128 frag reads). MFMA phase: h' = dinv * (a W), weights
// streamed from L2 (keeps VGPR low -> gather-phase occupancy preserved).

__device__ inline f32x2 h2f(__half2 v) {
    float2 t = __half22float2(v);
    return (f32x2){t.x, t.y};
}

// one node's gather-reduce; result in a0..a3 (caller owns accumulators)
#define GATHER_NODE(NODE_ON, IDX, END)                                          \
    {                                                                           \
        int4 sA, sB;                                                            \
        bool have8 = (IDX + 8 <= END);                                          \
        if (have8) {                                                            \
            sA = *(const int4*)(srcSorted + IDX);                               \
            sB = *(const int4*)(srcSorted + IDX + 4);                           \
        }                                                                       \
        while (have8) {                                                         \
            int4 cA = sA, cB = sB;                                              \
            int nidx = IDX + 8;                                                 \
            bool nxt = (nidx + 8 <= END);                                       \
            if (nxt) {                                                          \
                sA = *(const int4*)(srcSorted + nidx);                          \
                sB = *(const int4*)(srcSorted + nidx + 4);                      \
            }                                                                   \
            __half2 v0 = *(const __half2*)(hb + (unsigned)cA.x * 256u + fb);    \
            __half2 v1 = *(const __half2*)(hb + (unsigned)cA.y * 256u + fb);    \
            __half2 v2 = *(const __half2*)(hb + (unsigned)cA.z * 256u + fb);    \
            __half2 v3 = *(const __half2*)(hb + (unsigned)cA.w * 256u + fb);    \
            __half2 v4 = *(const __half2*)(hb + (unsigned)cB.x * 256u + fb);    \
            __half2 v5 = *(const __half2*)(hb + (unsigned)cB.y * 256u + fb);    \
            __half2 v6 = *(const __half2*)(hb + (unsigned)cB.z * 256u + fb);    \
            __half2 v7 = *(const __half2*)(hb + (unsigned)cB.w * 256u + fb);    \
            a0 += h2f(v0); a1 += h2f(v1); a2 += h2f(v2); a3 += h2f(v3);         \
            a0 += h2f(v4); a1 += h2f(v5); a2 += h2f(v6); a3 += h2f(v7);         \
            IDX = nidx;                                                         \
            have8 = nxt;                                                        \
        }                                                                       \
        if (IDX + 4 <= END) {                                                   \
            int4 cA = *(const int4*)(srcSorted + IDX);                          \
            __half2 v0 = *(const __half2*)(hb + (unsigned)cA.x * 256u + fb);    \
            __half2 v1 = *(const __half2*)(hb + (unsigned)cA.y * 256u + fb);    \
            __half2 v2 = *(const __half2*)(hb + (unsigned)cA.z * 256u + fb);    \
            __half2 v3 = *(const __half2*)(hb + (unsigned)cA.w * 256u + fb);    \
            a0 += h2f(v0); a1 += h2f(v1); a2 += h2f(v2); a3 += h2f(v3);         \
        }                                                                       \
    }

__global__ __launch_bounds__(256) void fused_agg_gemm128(const __half* __restrict__ hsrc,
                                                         const _Float16* __restrict__ wh,
                                                         const _Float16* __restrict__ wl,
                                                         const float* __restrict__ dinv,
                                                         const int* __restrict__ offsets,
                                                         const int* __restrict__ srcSorted,
                                                         const float* __restrict__ bias,
                                                         __half* __restrict__ hdst, int n) {
    __shared__ __align__(16) _Float16 aST[16 * 136];
    int wave = threadIdx.x >> 6;
    int lane = threadIdx.x & 63;
    int strip = blockIdx.x;
    int f = lane * 2;
    unsigned fb = (unsigned)f * 2u;
    const char* hb = (const char*)hsrc;
    float2 bv = *(const float2*)(bias + f);

    for (int i = 0; i < 4; i++) {
        int row = (wave << 2) + i;
        int node = (strip << 4) + row;
        bool on = (node < n);
        float di = on ? dinv[node] : 0.f;
        int idx = on ? offsets[node] : 0;
        int end = on ? offsets[node + 1] : 0;

        f32x2 z = (f32x2){0.f, 0.f};
        f32x2 a0 = z, a1 = z, a2 = z, a3 = z;
        if (on) a0 = h2f(*(const __half2*)(hb + (unsigned)node * 256u + fb));
        GATHER_NODE(on, idx, end);

        f32x2 s = (a0 + a1) + (a2 + a3);
        float ox = fmaxf(di * s.x + bv.x, 0.f);
        float oy = fmaxf(di * s.y + bv.y, 0.f);
        *(__half2*)(aST + row * 136 + f) = __floats2half2_rn(ox, oy);
    }
    __syncthreads();

    int quad = lane >> 4;
    int mm   = lane & 15;
    f16x8 av[4];
#pragma unroll
    for (int c = 0; c < 4; c++)
        av[c] = *(const f16x8*)(aST + mm * 136 + (c << 5) + (quad << 3));
    int rbase = (strip << 4) + (quad << 2);
    float dv[4];
#pragma unroll
    for (int r = 0; r < 4; r++) dv[r] = (rbase + r < n) ? dinv[rbase + r] : 0.f;

#pragma unroll
    for (int t2 = 0; t2 < 2; t2++) {
        int gt = (wave << 1) + t2;
        f32x4 acch = (f32x4){0.f, 0.f, 0.f, 0.f};
        f32x4 accl = (f32x4){0.f, 0.f, 0.f, 0.f};
#pragma unroll
        for (int c = 0; c < 4; c++) {
            int base = (((gt << 2) + c) << 6 | lane) << 3;
            f16x8 bh = *(const f16x8*)(wh + base);
            f16x8 bl = *(const f16x8*)(wl + base);
            acch = __builtin_amdgcn_mfma_f32_16x16x32_f16(av[c], bh, acch, 0, 0, 0);
            accl = __builtin_amdgcn_mfma_f32_16x16x32_f16(av[c], bl, accl, 0, 0, 0);
        }
#pragma unroll
        for (int r = 0; r < 4; r++) {
            if (rbase + r < n) {
                float v = acch[r] + accl[r] * (1.0f / 2048.0f);
                hdst[(size_t)(rbase + r) * 128 + (gt << 4) + mm] = __float2half(v * dv[r]);
            }
        }
    }
}

// Final layer: agg3 -> x_latent (fp32) + gemm40 -> h4' fp16 [N+1,40].
__global__ __launch_bounds__(256) void fused_agg_gemm40(const __half* __restrict__ hsrc,
                                                        const _Float16* __restrict__ wh,
                                                        const _Float16* __restrict__ wl,
                                                        const float* __restrict__ dinv,
                                                        const int* __restrict__ offsets,
                                                        const int* __restrict__ srcSorted,
                                                        const float* __restrict__ bias,
                                                        float* __restrict__ xlat,
                                                        __half* __restrict__ hdst, int n) {
    __shared__ __align__(16) _Float16 aST[16 * 136];
    int wave = threadIdx.x >> 6;
    int lane = threadIdx.x & 63;
    int strip = blockIdx.x;
    int f = lane * 2;
    unsigned fb = (unsigned)f * 2u;
    const char* hb = (const char*)hsrc;
    float2 bv = *(const float2*)(bias + f);

    if (blockIdx.x == 0 && threadIdx.x < 20) {   // zero h4' dummy row n
        ((__half2*)(hdst + (size_t)n * 40))[threadIdx.x] = __floats2half2_rn(0.f, 0.f);
    }

    for (int i = 0; i < 4; i++) {
        int row = (wave << 2) + i;
        int node = (strip << 4) + row;
        bool on = (node < n);
        float di = on ? dinv[node] : 0.f;
        int idx = on ? offsets[node] : 0;
        int end = on ? offsets[node + 1] : 0;

        f32x2 z = (f32x2){0.f, 0.f};
        f32x2 a0 = z, a1 = z, a2 = z, a3 = z;
        if (on) a0 = h2f(*(const __half2*)(hb + (unsigned)node * 256u + fb));
        GATHER_NODE(on, idx, end);

        f32x2 s = (a0 + a1) + (a2 + a3);
        float ox = fmaxf(di * s.x + bv.x, 0.f);
        float oy = fmaxf(di * s.y + bv.y, 0.f);
        if (on) *(float2*)(xlat + (size_t)node * 128 + f) = make_float2(ox, oy);
        *(__half2*)(aST + row * 136 + f) = __floats2half2_rn(ox, oy);
    }
    __syncthreads();

    if (wave < 3) {
        int quad = lane >> 4;
        int mm   = lane & 15;
        f16x8 av[4];
#pragma unroll
        for (int c = 0; c < 4; c++)
            av[c] = *(const f16x8*)(aST + mm * 136 + (c << 5) + (quad << 3));
        int rbase = (strip << 4) + (quad << 2);
        float dv[4];
#pragma unroll
        for (int r = 0; r < 4; r++) dv[r] = (rbase + r < n) ? dinv[rbase + r] : 0.f;

        int gt = wave;
        f32x4 acch = (f32x4){0.f, 0.f, 0.f, 0.f};
        f32x4 accl = (f32x4){0.f, 0.f, 0.f, 0.f};
#pragma unroll
        for (int c = 0; c < 4; c++) {
            int base = (((gt << 2) + c) << 6 | lane) << 3;
            f16x8 bh = *(const f16x8*)(wh + base);
            f16x8 bl = *(const f16x8*)(wl + base);
            acch = __builtin_amdgcn_mfma_f32_16x16x32_f16(av[c], bh, acch, 0, 0, 0);
            accl = __builtin_amdgcn_mfma_f32_16x16x32_f16(av[c], bl, accl, 0, 0, 0);
        }
        int col = (gt << 4) + mm;
#pragma unroll
        for (int r = 0; r < 4; r++) {
            if (rbase + r < n && col < 40) {
                float v = acch[r] + accl[r] * (1.0f / 2048.0f);
                hdst[(size_t)(rbase + r) * 40 + col] = __float2half(v * dv[r]);
            }
        }
    }
}

// NF=40 final agg: three nodes per wave, fp32 out, no relu.
__global__ __launch_bounds__(256) void agg40_tri(const __half* __restrict__ h,
                                                 const float* __restrict__ dinv,
                                                 const int* __restrict__ offsets,
                                                 const int* __restrict__ srcSorted,
                                                 const float* __restrict__ bias,
                                                 float* __restrict__ out, int n) {
    int wave = threadIdx.x >> 6;
    int lane = threadIdx.x & 63;
    unsigned sub = (unsigned)lane / 20u;
    int fi = lane - (int)sub * 20;
    bool act = (sub < 3u);
    int f = fi * 2;
    unsigned fb = (unsigned)fi * 4u;
    const char* hb = (const char*)h;
    float bx = act ? bias[f] : 0.f;
    float by = act ? bias[f + 1] : 0.f;
    int ntri = (n + 2) / 3;

    for (int p = blockIdx.x * 4 + wave; p < ntri; p += gridDim.x * 4) {
        int node = p * 3 + (int)sub;
        bool on = act && (node < n);
        float di = on ? dinv[node] : 0.f;
        int idx = on ? offsets[node] : 0;
        int end = on ? offsets[node + 1] : 0;

        f32x2 z = (f32x2){0.f, 0.f};
        f32x2 a0 = z, a1 = z, a2 = z, a3 = z;
        if (on) a0 = h2f(*(const __half2*)(hb + (unsigned)node * 80u + fb));

        while (__any(idx + 8 <= end)) {
            bool c = (idx + 8 <= end);
            if (c) {
                int4 sA = *(const int4*)(srcSorted + idx);
                int4 sB = *(const int4*)(srcSorted + idx + 4);
                a0 += h2f(*(const __half2*)(hb + (unsigned)sA.x * 80u + fb));
                a1 += h2f(*(const __half2*)(hb + (unsigned)sA.y * 80u + fb));
                a2 += h2f(*(const __half2*)(hb + (unsigned)sA.z * 80u + fb));
                a3 += h2f(*(const __half2*)(hb + (unsigned)sA.w * 80u + fb));
                a0 += h2f(*(const __half2*)(hb + (unsigned)sB.x * 80u + fb));
                a1 += h2f(*(const __half2*)(hb + (unsigned)sB.y * 80u + fb));
                a2 += h2f(*(const __half2*)(hb + (unsigned)sB.z * 80u + fb));
                a3 += h2f(*(const __half2*)(hb + (unsigned)sB.w * 80u + fb));
                idx += 8;
            }
        }
        if (idx + 4 <= end) {
            int4 sA = *(const int4*)(srcSorted + idx);
            a0 += h2f(*(const __half2*)(hb + (unsigned)sA.x * 80u + fb));
            a1 += h2f(*(const __half2*)(hb + (unsigned)sA.y * 80u + fb));
            a2 += h2f(*(const __half2*)(hb + (unsigned)sA.z * 80u + fb));
            a3 += h2f(*(const __half2*)(hb + (unsigned)sA.w * 80u + fb));
        }

        if (on) {
            f32x2 s = (a0 + a1) + (a2 + a3);
            float ox = di * s.x + bx;
            float oy = di * s.y + by;
            *(float2*)(out + (size_t)node * 40 + f) = make_float2(ox, oy);
        }
    }
}

// ---------------- orchestration ----------------

extern "C" void kernel_launch(void* const* d_in, const int* in_sizes, int n_in,
                              void* d_out, int out_size, void* d_ws, size_t ws_size,
                              hipStream_t stream) {
    const float* x  = (const float*)d_in[0];
    const int* edge = (const int*)d_in[1];
    const float* W1 = (const float*)d_in[2]; const float* b1 = (const float*)d_in[3];
    const float* W2 = (const float*)d_in[4]; const float* b2 = (const float*)d_in[5];
    const float* W3 = (const float*)d_in[6]; const float* b3 = (const float*)d_in[7];
    const float* W4 = (const float*)d_in[8]; const float* b4 = (const float*)d_in[9];

    const int N = in_sizes[0] / 128;      // 100000
    const int E = in_sizes[1] / 2;        // 1600000
    const int* src = edge;
    const int* dst = edge + E;

    float* out_final = (float*)d_out;                    // [N,40]
    float* x_latent  = (float*)d_out + (size_t)N * 40;   // [N,128]

    const int nbk = (N + BWIDTH - 1) >> BSHIFT;          // 782

    // workspace carve-up
    char* w = (char*)d_ws;
    int* counts    = (int*)w;  w += (size_t)N * 4;
    int* offsets   = (int*)w;  w += (size_t)(N + 4) * 4;
    float* dinv    = (float*)w; w += (size_t)N * 4;
    int* srcSorted = (int*)w;  w += (size_t)(E + 4 * N) * 4;
    int* blockSums = (int*)w;  w += (size_t)1024 * 4;
    int* bcur2     = (int*)w;  w += (size_t)8448 * 4;
    int* spillCnt  = (int*)w;  w += (size_t)64 * 4;
    short* wfrag   = (short*)w;    w += (size_t)2 * 16384 * 2;   // W1 {hi,lo} bf16
    _Float16* wf16 = (_Float16*)w; w += (size_t)4 * 16384 * 2;   // W2,W3 {hi,lo} f16
    _Float16* wf40 = (_Float16*)w; w += (size_t)2 * 6144 * 2;    // W4 {hi,lo} f16 48-col
    w = (char*)(((uintptr_t)w + 255) & ~(uintptr_t)255);
    __half* hA   = (__half*)w; w += (size_t)(N + 1) * 128 * 2;   // h-tables ping
    __half* hB16 = (__half*)w; w += (size_t)(N + 1) * 128 * 2;   // h-tables pong

    int2* cells = (int2*)hA;
    int2* spill = cells + (size_t)nbk * 8 * CELL_CAP;

    short* wh1 = wfrag;            short* wl1 = wfrag + 16384;
    _Float16* wh2 = wf16;          _Float16* wl2 = wf16 + 16384;
    _Float16* wh3 = wf16 + 32768;  _Float16* wl3 = wf16 + 49152;
    _Float16* wh4 = wf40;          _Float16* wl4 = wf40 + 6144;

    int nb = (N + 1023) / 1024;
    int p1b = (E + P1_CHUNK - 1) / P1_CHUNK;
    int nStrips = (N + 15) / 16;   // 6250

    hipMemsetAsync(bcur2, 0, (size_t)(8448 + 64) * 4, stream);
    pass1_bucket<<<p1b, 256, 0, stream>>>(src, dst, bcur2, cells, spill, spillCnt, nbk, E);
    count_cells<<<nbk, 256, 0, stream>>>(bcur2, cells, spill, spillCnt, counts, dinv, N);
    scan_phase1<<<nb, 256, 0, stream>>>(counts, blockSums, N);
    scan_phase2<<<1, 1024, 0, stream>>>(blockSums, nb);
    scan_phase3<<<nb, 256, 0, stream>>>(counts, blockSums, offsets, N);
    pass2_scatter<<<nbk, 256, 0, stream>>>(bcur2, cells, spill, spillCnt, offsets, srcSorted, N);

    prep_wfrag<<<64, 256, 0, stream>>>(W1, wh1, wl1, hA + (size_t)N * 128);
    prep_wfrag16<<<64, 256, 0, stream>>>(W2, wh2, wl2, hB16 + (size_t)N * 128);
    prep_wfrag16<<<64, 256, 0, stream>>>(W3, wh3, wl3, nullptr);
    prep_wfrag40<<<24, 256, 0, stream>>>(W4, wh4, wl4);

    dim3 gGemm(GEMM_GX, 2);

    gemm_mfma<<<gGemm, 256, 0, stream>>>(x, wh1, wl1, dinv, hA, N);                 // h1' -> hA
    fused_agg_gemm128<<<nStrips, 256, 0, stream>>>(hA, wh2, wl2, dinv, offsets,
                                                   srcSorted, b1, hB16, N);         // h2' -> hB16
    fused_agg_gemm128<<<nStrips, 256, 0, stream>>>(hB16, wh3, wl3, dinv, offsets,
                                                   srcSorted, b2, hA, N);           // h3' -> hA
    fused_agg_gemm40<<<nStrips, 256, 0, stream>>>(hA, wh4, wl4, dinv, offsets,
                                                  srcSorted, b3, x_latent, hB16, N); // x_latent + h4' -> hB16
    agg40_tri<<<2048, 256, 0, stream>>>(hB16, dinv, offsets, srcSorted, b4, out_final, N);
}